// Round 6
// baseline (12078.432 us; speedup 1.0000x reference)
//
#include <hip/hip_runtime.h>
#include <hip/hip_bf16.h>
#include <stdint.h>

// SubLSTM T=1024, B=64, H=512, GATE=3H, L=2 — fused 2-layer pipelined,
// round 6: tag-in-band exchange (1 LLC trip), paced conditional re-sweep.
//
// 8 batch-groups x 8 rows; 32 blocks/group (16 h-cols each, both layers;
// weights in VGPRs). Iteration i: L0 computes t=i, L1 computes t=i-1.
// Exchange: every ring dword = (bf16(h)<<16) | ((t+1)&0xFFFF)  — the data IS
// the flag. Producer fires relaxed agent-scope stores and moves on (no drain,
// no sentinel: each word is self-validating, so no inter-store ordering is
// needed). Consumer does batched agent-scope sweeps of the 32KB group tile;
// only words still stale are re-loaded on retry (per-word bitmask, two-phase
// so loads stay batched — round-2 lesson); s_sleep pacing caps LLC demand.
// Ring depth 4: slot s=t&3; within a replay slot tags are distinct mod 65536;
// across replays per-location load/load coherence forbids observing values
// older than already observed; rings are memset to 0 each call regardless.

#define TSTEPS 1024
#define BATCH  64
#define HID    512
#define GATE   1536
#define NGROUPS 8
#define GROWS   8
#define GCUS    32
#define NTHREADS 192
#define RDEPTH  4
#define RING_WORDS (RDEPTH*BATCH*HID)     // 256K u32 per ring (4 slots)
#define GTILE   (GROWS*HID)               // 4096 words per group per ring slot
#define SWEEPK  43                        // ceil(2*GTILE/NTHREADS)

typedef __attribute__((ext_vector_type(8))) short short8;
typedef __attribute__((ext_vector_type(4))) short short4v;
typedef __attribute__((ext_vector_type(4))) float floatx4;

__device__ __forceinline__ float sigmoidf_(float x) { return 1.0f / (1.0f + __expf(-x)); }

__device__ __forceinline__ unsigned short f2bf(float x) {
    union { float f; unsigned u; } v; v.f = x;
    unsigned r = v.u + 0x7FFFu + ((v.u >> 16) & 1u);   // RNE
    return (unsigned short)(r >> 16);
}

__device__ __forceinline__ short8 load_frag(const float* p) {
    floatx4 a = *(const floatx4*)p;
    floatx4 b = *(const floatx4*)(p + 4);
    short8 r;
#pragma unroll
    for (int j = 0; j < 4; ++j) { r[j] = (short)f2bf(a[j]); r[j+4] = (short)f2bf(b[j]); }
    return r;
}

__device__ __forceinline__ unsigned agent_ld(const unsigned* p) {
    return __hip_atomic_load(p, __ATOMIC_RELAXED, __HIP_MEMORY_SCOPE_AGENT);
}
__device__ __forceinline__ void agent_st(unsigned* p, unsigned v) {
    __hip_atomic_store(p, v, __ATOMIC_RELAXED, __HIP_MEMORY_SCOPE_AGENT);
}

// ---- preamble: x f32 -> bf16 ----
__global__ __launch_bounds__(256) void xconvert(const float* __restrict__ x,
                                                unsigned short* __restrict__ xb) {
    const size_t i = ((size_t)blockIdx.x*256 + threadIdx.x) * 8;
    floatx4 a = *(const floatx4*)(x + i);
    floatx4 b = *(const floatx4*)(x + i + 4);
    short8 p;
#pragma unroll
    for (int j = 0; j < 4; ++j) { p[j] = (short)f2bf(a[j]); p[j+4] = (short)f2bf(b[j]); }
    *(short8*)(xb + i) = p;
}

__global__ __launch_bounds__(NTHREADS, 1) void sublstm_fused(
    const unsigned short* __restrict__ xb,
    const float* __restrict__ W,
    const float* __restrict__ R,
    const float* __restrict__ bi,
    const float* __restrict__ bh,
    const float* __restrict__ fw,
    const float* __restrict__ h0,
    const float* __restrict__ c0,
    unsigned* __restrict__ ring0,
    unsigned* __restrict__ ring1,
    float* __restrict__ out)
{
    const int tid  = threadIdx.x;
    const int lane = tid & 63;
    const int wid  = tid >> 6;           // 0=i_g, 1=o_g, 2=z (gate owner)
    const int bid  = blockIdx.x;
    const int g    = bid & 7;            // batch group (XCD-affine heuristic only)
    const int idx  = bid >> 3;           // 0..31: 16-col slice within group
    const int col0 = idx << 4;

    __shared__ __align__(16) unsigned short x_tile[16][520];
    __shared__ __align__(16) unsigned short hA[16][520];    // h0_{i-1}
    __shared__ __align__(16) unsigned short hB[16][520];    // h1_{i-2}
    __shared__ float proj[2][3][16][17];

    for (int i = tid; i < 16*520; i += NTHREADS) {
        ((unsigned short*)x_tile)[i] = 0;
        ((unsigned short*)hA)[i] = 0;
        ((unsigned short*)hB)[i] = 0;
    }

    const int lrow = lane & 15;
    const int lk   = (lane >> 4) << 3;
    const int wrow = wid*HID + col0 + lrow;

    // ---- weights for both layers in regs (128 VGPRs) ----
    short8 wf0[16], rf0[16], wf1[16], rf1[16];
#pragma unroll
    for (int kc = 0; kc < 16; ++kc) {
        wf0[kc] = load_frag(W + (size_t)wrow*HID + kc*32 + lk);
        rf0[kc] = load_frag(R + (size_t)wrow*HID + kc*32 + lk);
        wf1[kc] = load_frag(W + ((size_t)GATE + wrow)*HID + kc*32 + lk);
        rf1[kc] = load_frag(R + ((size_t)GATE + wrow)*HID + kc*32 + lk);
    }
    const float bias0 = bi[wrow] + bh[wrow];
    const float bias1 = bi[GATE + wrow] + bh[GATE + wrow];

    const int ecol  = lrow;
    const int erow0 = (lane >> 4) << 2;
    const int myl = (wid == 1) ? 1 : 0;
    const float fgv = sigmoidf_(fw[(size_t)myl*HID + col0 + ecol]);
    float creg[4];
#pragma unroll
    for (int q = 0; q < 4; ++q) {
        int r = erow0 + q;
        creg[q] = (r < GROWS) ? c0[((size_t)myl*BATCH + g*GROWS + r)*HID + col0 + ecol] : 0.0f;
    }

    // ---- stage x_0 (bf16) and h0 inits ----
    {
        const unsigned short* xp = xb + (size_t)g*GROWS*HID;
        for (int w = tid; w < GROWS*HID/8; w += NTHREADS) {
            int r = w >> 6, c8 = (w & 63) << 3;
            *(short8*)(&x_tile[r][c8]) = *(const short8*)(xp + (size_t)r*HID + c8);
        }
        const float* hp0 = h0 + (size_t)g*GROWS*HID;
        const float* hp1 = h0 + ((size_t)BATCH + g*GROWS)*HID;
        for (int w = tid; w < GROWS*HID/4; w += NTHREADS) {
            int r = w >> 7, c4 = (w & 127) << 2;
            floatx4 va_ = *(const floatx4*)(hp0 + (size_t)r*HID + c4);
            floatx4 vb_ = *(const floatx4*)(hp1 + (size_t)r*HID + c4);
            short4v pa, pb;
#pragma unroll
            for (int j = 0; j < 4; ++j) { pa[j] = (short)f2bf(va_[j]); pb[j] = (short)f2bf(vb_[j]); }
            *(short4v*)(&hA[r][c4]) = pa;
            *(short4v*)(&hB[r][c4]) = pb;
        }
    }
    __syncthreads();

    int budget = 1 << 22;   // sweep budget (bail -> visible failure, no hang)

    for (int i = 0; i <= TSTEPS; ++i) {
        // ---- Phase 1: gate GEMMs (4 independent MFMA chains) ----
        floatx4 a0a = {0,0,0,0}, a0b = {0,0,0,0}, a1a = {0,0,0,0}, a1b = {0,0,0,0};
#pragma unroll
        for (int kc = 0; kc < 16; ++kc) {
            short8 afh = *(const short8*)(&hA[lrow][kc*32 + lk]);
            if (i < TSTEPS) {
                short8 afx = *(const short8*)(&x_tile[lrow][kc*32 + lk]);
                a0a = __builtin_amdgcn_mfma_f32_16x16x32_bf16(afx, wf0[kc], a0a, 0, 0, 0);
                a0b = __builtin_amdgcn_mfma_f32_16x16x32_bf16(afh, rf0[kc], a0b, 0, 0, 0);
            }
            if (i >= 1) {
                short8 afb = *(const short8*)(&hB[lrow][kc*32 + lk]);
                a1a = __builtin_amdgcn_mfma_f32_16x16x32_bf16(afh, wf1[kc], a1a, 0, 0, 0);
                a1b = __builtin_amdgcn_mfma_f32_16x16x32_bf16(afb, rf1[kc], a1b, 0, 0, 0);
            }
        }
#pragma unroll
        for (int q = 0; q < 4; ++q) {
            proj[0][wid][erow0 + q][ecol] = sigmoidf_(a0a[q] + a0b[q] + bias0);
            proj[1][wid][erow0 + q][ecol] = sigmoidf_(a1a[q] + a1b[q] + bias1);
        }
        __syncthreads();   // B1

        // ---- Phase 2: state update + in-band tagged publish (no drain!) ----
        if (wid < 2) {
            const int t = i - wid;
            if (t >= 0 && t < TSTEPS) {
                unsigned* ring = (wid == 0) ? ring0 : ring1;
                const unsigned tag = (unsigned)(t + 1) & 0xFFFFu;
                unsigned* rbase = ring + ((size_t)((t & 3)*NGROUPS + g)*GROWS)*HID;
                float hv[4], cv[4];
#pragma unroll
                for (int q = 0; q < 4; ++q) {
                    const int r = erow0 + q;
                    const float ig = proj[wid][0][r][ecol];
                    const float og = proj[wid][1][r][ecol];
                    const float zz = proj[wid][2][r][ecol];
                    const float c  = creg[q]*fgv + zz - ig;
                    creg[q] = c;
                    const float h  = sigmoidf_(c) - og;
                    hv[q] = h; cv[q] = c;
                    if (r < GROWS)   // lanes 0..31 publish; critical path first
                        agent_st(rbase + (size_t)r*HID + col0 + ecol,
                                 ((unsigned)f2bf(h) << 16) | tag);
                }
                // off-critical-path stores
#pragma unroll
                for (int q = 0; q < 4; ++q) {
                    const int r = erow0 + q;
                    if (r < GROWS) {
                        if (wid == 1)
                            out[((size_t)t*BATCH + g*GROWS + r)*HID + col0 + ecol] = hv[q];
                        if (t == TSTEPS - 1) {
                            const size_t fo = (size_t)TSTEPS*BATCH*HID
                                            + ((size_t)wid*BATCH + g*GROWS + r)*HID + col0 + ecol;
                            out[fo] = hv[q];                        // h_f
                            out[fo + (size_t)2*BATCH*HID] = cv[q];  // c_f
                        }
                    }
                }
            }
            // stage x_{i+1} (waves 0/1, 128 threads cover 512 x8-words)
            if (i + 1 < TSTEPS) {
                const unsigned short* xp = xb + ((size_t)(i+1)*BATCH + g*GROWS)*HID;
#pragma unroll
                for (int k = 0; k < 4; ++k) {
                    const int w = tid + k*128;
                    if (w < GROWS*HID/8) {
                        const int r = w >> 6, c8 = (w & 63) << 3;
                        *(short8*)(&x_tile[r][c8]) = *(const short8*)(xp + (size_t)r*HID + c8);
                    }
                }
            }
        }

        // ---- Phase 3: paced conditional tag sweep (detect == fetch) ----
        if (i < TSTEPS) {
            const int nw = (i >= 1) ? 2*GTILE : GTILE;
            const unsigned wantA = (unsigned)(i + 1) & 0xFFFFu;
            const unsigned wantB = (unsigned)i & 0xFFFFu;
            const unsigned* pA = ring0 + ((size_t)((i & 3)*NGROUPS + g)*GROWS)*HID;
            const unsigned* pB = ring1 + ((size_t)(((i - 1) & 3)*NGROUPS + g)*GROWS)*HID;
            unsigned va[SWEEPK];
            uint64_t okm = 0;
#pragma unroll
            for (int k = 0; k < SWEEPK; ++k)
                if (tid + k*NTHREADS >= nw) okm |= (1ull << k);
            const uint64_t FULL = (SWEEPK < 64) ? ((1ull << SWEEPK) - 1) : ~0ull;

            if (wid == 2) __builtin_amdgcn_s_sleep(16);   // producers haven't fired yet
            while (true) {
                // Phase A: batched (re)loads of stale words only
#pragma unroll
                for (int k = 0; k < SWEEPK; ++k) {
                    const int w = tid + k*NTHREADS;
                    if (w < nw && !(okm & (1ull << k)))
                        va[k] = agent_ld((w < GTILE) ? (pA + w) : (pB + (w - GTILE)));
                }
                // Phase B: tag checks
                uint64_t m = okm;
#pragma unroll
                for (int k = 0; k < SWEEPK; ++k) {
                    const int w = tid + k*NTHREADS;
                    if (w < nw && !(okm & (1ull << k))) {
                        const unsigned want = (w < GTILE) ? wantA : wantB;
                        if ((va[k] & 0xFFFFu) == want) m |= (1ull << k);
                    }
                }
                okm = m;
                if (__all((int)(okm == FULL)) || --budget <= 0) break;
                __builtin_amdgcn_s_sleep(8);
            }

            // stash into LDS tiles
#pragma unroll
            for (int k = 0; k < SWEEPK; ++k) {
                const int w = tid + k*NTHREADS;
                if (w < nw) {
                    const unsigned short hv = (unsigned short)(va[k] >> 16);
                    if (w < GTILE) { hA[w >> 9][w & 511] = hv; }
                    else { const int w1 = w - GTILE; hB[w1 >> 9][w1 & 511] = hv; }
                }
            }
        }
        __syncthreads();   // B4
    }
}

extern "C" void kernel_launch(void* const* d_in, const int* in_sizes, int n_in,
                              void* d_out, int out_size, void* d_ws, size_t ws_size,
                              hipStream_t stream)
{
    (void)in_sizes; (void)n_in; (void)out_size; (void)ws_size;
    const float* x  = (const float*)d_in[0];
    const float* h0 = (const float*)d_in[1];
    const float* c0 = (const float*)d_in[2];
    const float* W  = (const float*)d_in[3];
    const float* R  = (const float*)d_in[4];
    const float* bi = (const float*)d_in[5];
    const float* bh = (const float*)d_in[6];
    const float* fw = (const float*)d_in[7];
    float* out = (float*)d_out;

    unsigned* ring0 = (unsigned*)d_ws;                                  // 1 MB
    unsigned* ring1 = ring0 + RING_WORDS;                               // 1 MB
    unsigned short* xbuf = (unsigned short*)((char*)d_ws + (4u << 20)); // 64 MB

    hipMemsetAsync(d_ws, 0, (size_t)2*RING_WORDS*4, stream);  // rings := tag 0

    xconvert<<<dim3(TSTEPS*BATCH*HID/(256*8)), dim3(256), 0, stream>>>(x, xbuf);

    sublstm_fused<<<dim3(NGROUPS*GCUS), dim3(NTHREADS), 0, stream>>>(
        xbuf, W, R, bi, bh, fw, h0, c0, ring0, ring1, out);
}

// Round 7
// 6130.955 us; speedup vs baseline: 1.9701x; 1.9701x over previous
//
#include <hip/hip_runtime.h>
#include <hip/hip_bf16.h>
#include <stdint.h>

// SubLSTM T=1024, B=64, H=512, GATE=3H, L=2 — fused 2-layer pipelined,
// round 7: trimmed sentinel protocol, 4-wave blocks, 1 state cell/thread.
//
// 8 groups x 8 batch rows; 32 blocks/group (16 h-cols, both layers).
// Iteration i: L0 computes t=i, L1 computes t=i-1.
// Waves 0-2: gate GEMMs (i/o/z) with weights in regs. Wave 3: sentinel poll.
// All 4 waves: state update (1 cell/thread), packed publish, per-wave
// store-release (own vmcnt(0) drain -> own sentinel; LLVM's agent-release
// lowering), batched data sweep.
// Protocol per round: publish packed h (1 agent store/even lane) -> per-wave
// drain -> per-wave sentinel -> wave3 polls 2x64 sentinels (>= tolerates
// 1-round run-ahead; skew bounded at 1 round by the poll itself) -> B3 ->
// all threads sweep 16 dword atomics -> stash LDS -> B4.
// Replay-safe: sentinels memset 0 each call; ring reads gated by sentinels.

#define TSTEPS 1024
#define BATCH  64
#define HID    512
#define GATE   1536
#define NGROUPS 8
#define GROWS   8
#define NT      256
#define NBLOCKS 256

typedef __attribute__((ext_vector_type(8))) short short8;
typedef __attribute__((ext_vector_type(4))) short short4v;
typedef __attribute__((ext_vector_type(4))) float floatx4;

__device__ __forceinline__ float sigmoidf_(float x) { return 1.0f / (1.0f + __expf(-x)); }

__device__ __forceinline__ unsigned short f2bf(float x) {
    union { float f; unsigned u; } v; v.f = x;
    unsigned r = v.u + 0x7FFFu + ((v.u >> 16) & 1u);   // RNE
    return (unsigned short)(r >> 16);
}

__device__ __forceinline__ short8 load_frag(const float* p) {
    floatx4 a = *(const floatx4*)p;
    floatx4 b = *(const floatx4*)(p + 4);
    short8 r;
#pragma unroll
    for (int j = 0; j < 4; ++j) { r[j] = (short)f2bf(a[j]); r[j+4] = (short)f2bf(b[j]); }
    return r;
}

__device__ __forceinline__ unsigned agent_ld(const unsigned* p) {
    return __hip_atomic_load(p, __ATOMIC_RELAXED, __HIP_MEMORY_SCOPE_AGENT);
}
__device__ __forceinline__ void agent_st(unsigned* p, unsigned v) {
    __hip_atomic_store(p, v, __ATOMIC_RELAXED, __HIP_MEMORY_SCOPE_AGENT);
}

__global__ __launch_bounds__(NT, 1) void sublstm_fused(
    const float* __restrict__ x,
    const float* __restrict__ W,
    const float* __restrict__ R,
    const float* __restrict__ bi,
    const float* __restrict__ bh,
    const float* __restrict__ fw,
    const float* __restrict__ h0,
    const float* __restrict__ c0,
    unsigned* __restrict__ sent,    // [2][8][64] u32, 16B stride
    unsigned* __restrict__ ring,    // [2][4][8][8][256] packed dwords
    float* __restrict__ out)
{
    const int tid  = threadIdx.x;
    const int lane = tid & 63;
    const int wid  = tid >> 6;            // 0,1,2 = i/o/z gate waves; 3 = poller
    const int bid  = blockIdx.x;
    const int g    = bid & 7;             // batch group
    const int bidx = bid >> 3;            // 0..31: 16-col slice
    const int col0 = bidx << 4;

    __shared__ __align__(16) unsigned short x_tile[2][16][520];
    __shared__ __align__(16) unsigned short hA[16][520];    // h0_{i-1}
    __shared__ __align__(16) unsigned short hB[16][520];    // h1_{i-2}
    __shared__ float proj[2][3][16][17];

    for (int i = tid; i < 2*16*520; i += NT) ((unsigned short*)x_tile)[i] = 0;
    for (int i = tid; i < 16*520; i += NT) {
        ((unsigned short*)hA)[i] = 0;
        ((unsigned short*)hB)[i] = 0;
    }

    const int lrow = lane & 15;
    const int lk   = (lane >> 4) << 3;

    // ---- weights for both layers in regs (gate waves only) ----
    short8 wf0[16], rf0[16], wf1[16], rf1[16];
    float bias0 = 0.f, bias1 = 0.f;
    if (wid < 3) {
        const int wrow = wid*HID + col0 + lrow;
#pragma unroll
        for (int kc = 0; kc < 16; ++kc) {
            wf0[kc] = load_frag(W + (size_t)wrow*HID + kc*32 + lk);
            rf0[kc] = load_frag(R + (size_t)wrow*HID + kc*32 + lk);
            wf1[kc] = load_frag(W + ((size_t)GATE + wrow)*HID + kc*32 + lk);
            rf1[kc] = load_frag(R + ((size_t)GATE + wrow)*HID + kc*32 + lk);
        }
        bias0 = bi[wrow] + bh[wrow];
        bias1 = bi[GATE + wrow] + bh[GATE + wrow];
    }

    // ---- state: 1 cell per thread ----
    const int lyr  = tid >> 7;            // waves 0,1 -> L0; waves 2,3 -> L1
    const int srow = (tid >> 4) & 7;
    const int scol = tid & 15;
    const int wsl  = (tid >> 6) & 1;      // wave index within layer
    const float fgv = sigmoidf_(fw[(size_t)lyr*HID + col0 + scol]);
    float creg = c0[((size_t)lyr*BATCH + g*GROWS + srow)*HID + col0 + scol];

    // ---- prologue: stage x_0 and h0 tiles (f32 -> bf16) ----
    {
        const float* xp  = x + (size_t)g*GROWS*HID;
        const float* hp0 = h0 + (size_t)g*GROWS*HID;
        const float* hp1 = h0 + ((size_t)BATCH + g*GROWS)*HID;
        for (int w = tid; w < GROWS*HID/4; w += NT) {
            const int r = w >> 7, c4 = (w & 127) << 2;
            floatx4 vx = *(const floatx4*)(xp  + (size_t)r*HID + c4);
            floatx4 va_ = *(const floatx4*)(hp0 + (size_t)r*HID + c4);
            floatx4 vb_ = *(const floatx4*)(hp1 + (size_t)r*HID + c4);
            short4v px, pa, pb;
#pragma unroll
            for (int j = 0; j < 4; ++j) {
                px[j] = (short)f2bf(vx[j]); pa[j] = (short)f2bf(va_[j]); pb[j] = (short)f2bf(vb_[j]);
            }
            *(short4v*)(&x_tile[0][r][c4]) = px;
            *(short4v*)(&hA[r][c4]) = pa;
            *(short4v*)(&hB[r][c4]) = pb;
        }
    }
    __syncthreads();

    int budget = 1 << 22;

    for (int i = 0; i <= TSTEPS; ++i) {
        // ---- Phase 1: gate GEMMs (waves 0-2; 4 independent MFMA chains) ----
        if (wid < 3) {
            floatx4 a0a = {0,0,0,0}, a0b = {0,0,0,0}, a1a = {0,0,0,0}, a1b = {0,0,0,0};
            const int xp = i & 1;
#pragma unroll
            for (int kc = 0; kc < 16; ++kc) {
                short8 afh = *(const short8*)(&hA[lrow][kc*32 + lk]);
                if (i < TSTEPS) {
                    short8 afx = *(const short8*)(&x_tile[xp][lrow][kc*32 + lk]);
                    a0a = __builtin_amdgcn_mfma_f32_16x16x32_bf16(afx, wf0[kc], a0a, 0, 0, 0);
                    a0b = __builtin_amdgcn_mfma_f32_16x16x32_bf16(afh, rf0[kc], a0b, 0, 0, 0);
                }
                if (i >= 1) {
                    short8 afb = *(const short8*)(&hB[lrow][kc*32 + lk]);
                    a1a = __builtin_amdgcn_mfma_f32_16x16x32_bf16(afh, wf1[kc], a1a, 0, 0, 0);
                    a1b = __builtin_amdgcn_mfma_f32_16x16x32_bf16(afb, rf1[kc], a1b, 0, 0, 0);
                }
            }
            const int erow0 = (lane >> 4) << 2, ecol = lrow;
#pragma unroll
            for (int q = 0; q < 4; ++q) {
                proj[0][wid][erow0 + q][ecol] = sigmoidf_(a0a[q] + a0b[q] + bias0);
                proj[1][wid][erow0 + q][ecol] = sigmoidf_(a1a[q] + a1b[q] + bias1);
            }
        }
        __syncthreads();   // B1

        // ---- Phase 2: state update (1 cell/thread) + publish + release ----
        const int t = i - lyr;
        const bool act = lyr ? (i >= 1) : (i < TSTEPS);
        float h_ = 0.f, c_ = 0.f;
        if (act) {
            const float ig = proj[lyr][0][srow][scol];
            const float og = proj[lyr][1][srow][scol];
            const float zz = proj[lyr][2][srow][scol];
            c_ = creg*fgv + zz - ig;
            creg = c_;
            h_ = sigmoidf_(c_) - og;
            if (i < TSTEPS) {
                const unsigned hu = __float_as_uint(h_);
                const unsigned pu = (unsigned)__builtin_amdgcn_ds_swizzle((int)hu, 0x041F);
                unsigned word;
                asm volatile("v_cvt_pk_bf16_f32 %0, %1, %2"
                             : "=v"(word) : "v"(h_), "v"(__uint_as_float(pu)));
                if (!(scol & 1))
                    agent_st(ring + ((size_t)(lyr*4 + (t & 3))*8 + g)*2048
                                  + srow*256 + ((col0 + scol) >> 1), word);
            }
        }
        if (i < TSTEPS) {
            // per-wave store-release: own stores ack'd, then own sentinel
            asm volatile("s_waitcnt vmcnt(0)" ::: "memory");
            if (lane == 0)
                agent_st(sent + (((size_t)lyr*8 + g)*64 + (bidx << 1) + wsl)*4,
                         (unsigned)(t + 1));
        }
        const bool defer = (wid == 3) && (i < TSTEPS);
        if (act && lyr == 1 && !defer)
            out[((size_t)t*BATCH + g*GROWS + srow)*HID + col0 + scol] = h_;
        if (act && t == TSTEPS - 1 && !defer) {
            const size_t fo = (size_t)TSTEPS*BATCH*HID
                            + ((size_t)lyr*BATCH + g*GROWS + srow)*HID + col0 + scol;
            out[fo] = h_;                               // h_f
            out[fo + (size_t)2*BATCH*HID] = c_;         // c_f
        }

        // ---- Phase 3: wave 3 polls 2x64 sentinels ----
        if (wid == 3 && i < TSTEPS) {
            const unsigned want0 = (unsigned)(i + 1);
            const unsigned want1 = (unsigned)i;
            const unsigned* p0 = sent + ((size_t)g*64 + lane)*4;          // L0
            const unsigned* p1 = sent + ((size_t)(8 + g)*64 + lane)*4;    // L1
            while (true) {
                const unsigned v0 = agent_ld(p0);
                const unsigned v1 = agent_ld(p1);
                if (__all((int)((v0 >= want0) && (v1 >= want1))) || --budget <= 0) break;
            }
        }
        __syncthreads();   // B3: all group data LLC-visible

        // ---- Phase 4: batched sweep + x prefetch + stash ----
        if (i < TSTEPS) {
            const size_t b0 = ((size_t)(i & 3)*8 + g)*2048;              // L0 slot
            const size_t b1 = ((size_t)(4 + ((i - 1) & 3))*8 + g)*2048;  // L1 slot
            const int nw = (i >= 1) ? 4096 : 2048;
            unsigned va[16];
#pragma unroll
            for (int k = 0; k < 16; ++k) {
                const int w = tid + (k << 8);
                if (w < nw)
                    va[k] = agent_ld(ring + ((w < 2048) ? (b0 + w) : (b1 + (w - 2048))));
            }
            floatx4 xr[6];
            const bool havex = (tid < 192) && (i + 1 < TSTEPS);
            if (havex) {
                const float* xp = x + ((size_t)(i + 1)*BATCH + g*GROWS)*HID;
#pragma unroll
                for (int k = 0; k < 6; ++k) {
                    const int idx = tid + k*192;
                    if (idx < 1024)
                        xr[k] = *(const floatx4*)(xp + (size_t)(idx >> 7)*HID + ((idx & 127) << 2));
                }
            }
            if (act && defer) {   // wave3's deferred out stores (lyr==1)
                out[((size_t)t*BATCH + g*GROWS + srow)*HID + col0 + scol] = h_;
                if (t == TSTEPS - 1) {
                    const size_t fo = (size_t)TSTEPS*BATCH*HID
                                    + ((size_t)BATCH + g*GROWS + srow)*HID + col0 + scol;
                    out[fo] = h_;
                    out[fo + (size_t)2*BATCH*HID] = c_;
                }
            }
#pragma unroll
            for (int k = 0; k < 16; ++k) {
                const int w = tid + (k << 8);
                if (w < nw) {
                    const int r = (w >> 8) & 7, pc = w & 255;
                    if (w < 2048) *(unsigned*)(&hA[r][pc << 1]) = va[k];
                    else          *(unsigned*)(&hB[r][pc << 1]) = va[k];
                }
            }
            if (havex) {
                const int xq = (i + 1) & 1;
#pragma unroll
                for (int k = 0; k < 6; ++k) {
                    const int idx = tid + k*192;
                    if (idx < 1024) {
                        short4v p4;
#pragma unroll
                        for (int j = 0; j < 4; ++j) p4[j] = (short)f2bf(xr[k][j]);
                        *(short4v*)(&x_tile[xq][idx >> 7][(idx & 127) << 2]) = p4;
                    }
                }
            }
        }
        __syncthreads();   // B4
    }
}

extern "C" void kernel_launch(void* const* d_in, const int* in_sizes, int n_in,
                              void* d_out, int out_size, void* d_ws, size_t ws_size,
                              hipStream_t stream)
{
    (void)in_sizes; (void)n_in; (void)out_size; (void)ws_size;
    const float* x  = (const float*)d_in[0];
    const float* h0 = (const float*)d_in[1];
    const float* c0 = (const float*)d_in[2];
    const float* W  = (const float*)d_in[3];
    const float* R  = (const float*)d_in[4];
    const float* bi = (const float*)d_in[5];
    const float* bh = (const float*)d_in[6];
    const float* fw = (const float*)d_in[7];
    float* out = (float*)d_out;

    unsigned* sent = (unsigned*)d_ws;                         // 16 KB (2*8*64 x 16B)
    unsigned* ring = (unsigned*)((char*)d_ws + 65536);        // 512 KB

    hipMemsetAsync(d_ws, 0, 16384, stream);   // sentinels := 0 (replay-safe)

    sublstm_fused<<<dim3(NBLOCKS), dim3(NT), 0, stream>>>(
        x, W, R, bi, bh, fw, h0, c0, sent, ring, out);
}

// Round 8
// 5171.895 us; speedup vs baseline: 2.3354x; 1.1854x over previous
//
#include <hip/hip_runtime.h>
#include <hip/hip_bf16.h>
#include <stdint.h>

// SubLSTM T=1024, B=64, H=512, GATE=3H, L=2 — fused 2-layer pipelined,
// round 8: one-trip in-band protocol (u64 payload|tag), no drain/sentinel/poll.
//
// 8 groups x 8 batch rows; 32 blocks/group (16 h-cols, both layers).
// Iteration i: L0 computes t=i, L1 computes t=i-1 (lag-1 layer pipeline).
// Exchange unit: u64 = (tag32 << 32) | (2 x bf16 payload), written/read with
// relaxed agent-scope u64 atomics (single-copy atomic; the data IS the flag).
// Per round: publish own u64s (no ordering needed) -> issue full batched sweep
// of both group tiles (16 u64/thread) -> issue x prefetch -> tag-check (the
// compiler's vmcnt wait covers publish acks too, in-order, same trip) ->
// batched conditional retries (stale words only, no s_sleep) -> LDS stash ->
// out stores (HBM acks drain during next round, off the critical wait) -> B4.
// Ring depth 4; skew <= 3 by sweep-all coupling => no within-replay tag alias;
// 32-bit tags; cross-replay stale accepts return bit-identical deterministic
// payloads (same inputs -> same h), 0xAA poison never matches a wanted tag.

#define TSTEPS 1024
#define BATCH  64
#define HID    512
#define GATE   1536
#define GROWS  8
#define NT     256
#define NBLOCKS 256

typedef unsigned long long u64;
typedef __attribute__((ext_vector_type(8))) short short8;
typedef __attribute__((ext_vector_type(4))) short short4v;
typedef __attribute__((ext_vector_type(4))) float floatx4;

__device__ __forceinline__ float sigmoidf_(float x) { return 1.0f / (1.0f + __expf(-x)); }

__device__ __forceinline__ unsigned short f2bf(float x) {
    union { float f; unsigned u; } v; v.f = x;
    unsigned r = v.u + 0x7FFFu + ((v.u >> 16) & 1u);   // RNE
    return (unsigned short)(r >> 16);
}

__device__ __forceinline__ short8 load_frag(const float* p) {
    floatx4 a = *(const floatx4*)p;
    floatx4 b = *(const floatx4*)(p + 4);
    short8 r;
#pragma unroll
    for (int j = 0; j < 4; ++j) { r[j] = (short)f2bf(a[j]); r[j+4] = (short)f2bf(b[j]); }
    return r;
}

__device__ __forceinline__ u64 ring_ld(const u64* p) {
    return __hip_atomic_load(p, __ATOMIC_RELAXED, __HIP_MEMORY_SCOPE_AGENT);
}
__device__ __forceinline__ void ring_st(u64* p, u64 v) {
    __hip_atomic_store(p, v, __ATOMIC_RELAXED, __HIP_MEMORY_SCOPE_AGENT);
}

__global__ __launch_bounds__(NT, 1) void sublstm_fused(
    const float* __restrict__ x,
    const float* __restrict__ W,
    const float* __restrict__ R,
    const float* __restrict__ bi,
    const float* __restrict__ bh,
    const float* __restrict__ fw,
    const float* __restrict__ h0,
    const float* __restrict__ c0,
    u64* __restrict__ ring,        // [lyr 2][slot 4][grp 8][blk 32][row 8][unit 8]
    float* __restrict__ out)
{
    const int tid  = threadIdx.x;
    const int lane = tid & 63;
    const int wid  = tid >> 6;            // 0,1,2 = i/o/z gate waves; 3 = helper
    const int bid  = blockIdx.x;
    const int g    = bid & 7;             // batch group
    const int bidx = bid >> 3;            // 0..31: 16-col slice
    const int col0 = bidx << 4;

    __shared__ __align__(16) unsigned short x_tile[2][16][520];
    __shared__ __align__(16) unsigned short hA[16][520];    // h0_{i-1}
    __shared__ __align__(16) unsigned short hB[16][520];    // h1_{i-2}
    __shared__ float proj[2][3][16][17];

    for (int i = tid; i < 2*16*520; i += NT) ((unsigned short*)x_tile)[i] = 0;
    for (int i = tid; i < 16*520; i += NT) {
        ((unsigned short*)hA)[i] = 0;
        ((unsigned short*)hB)[i] = 0;
    }

    const int lrow = lane & 15;
    const int lk   = (lane >> 4) << 3;

    // ---- weights for both layers in regs (gate waves only) ----
    short8 wf0[16], rf0[16], wf1[16], rf1[16];
    float bias0 = 0.f, bias1 = 0.f;
    if (wid < 3) {
        const int wrow = wid*HID + col0 + lrow;
#pragma unroll
        for (int kc = 0; kc < 16; ++kc) {
            wf0[kc] = load_frag(W + (size_t)wrow*HID + kc*32 + lk);
            rf0[kc] = load_frag(R + (size_t)wrow*HID + kc*32 + lk);
            wf1[kc] = load_frag(W + ((size_t)GATE + wrow)*HID + kc*32 + lk);
            rf1[kc] = load_frag(R + ((size_t)GATE + wrow)*HID + kc*32 + lk);
        }
        bias0 = bi[wrow] + bh[wrow];
        bias1 = bi[GATE + wrow] + bh[GATE + wrow];
    }

    // ---- state: 1 cell per thread ----
    const int lyr  = tid >> 7;            // waves 0,1 -> L0; waves 2,3 -> L1
    const int srow = (tid >> 4) & 7;
    const int scol = tid & 15;
    const float fgv = sigmoidf_(fw[(size_t)lyr*HID + col0 + scol]);
    float creg = c0[((size_t)lyr*BATCH + g*GROWS + srow)*HID + col0 + scol];

    // ---- prologue: stage x_0 and h0 tiles (f32 -> bf16) ----
    {
        const float* xp  = x + (size_t)g*GROWS*HID;
        const float* hp0 = h0 + (size_t)g*GROWS*HID;
        const float* hp1 = h0 + ((size_t)BATCH + g*GROWS)*HID;
        for (int w = tid; w < GROWS*HID/4; w += NT) {
            const int r = w >> 7, c4 = (w & 127) << 2;
            floatx4 vx = *(const floatx4*)(xp  + (size_t)r*HID + c4);
            floatx4 va_ = *(const floatx4*)(hp0 + (size_t)r*HID + c4);
            floatx4 vb_ = *(const floatx4*)(hp1 + (size_t)r*HID + c4);
            short4v px, pa, pb;
#pragma unroll
            for (int j = 0; j < 4; ++j) {
                px[j] = (short)f2bf(vx[j]); pa[j] = (short)f2bf(va_[j]); pb[j] = (short)f2bf(vb_[j]);
            }
            *(short4v*)(&x_tile[0][r][c4]) = px;
            *(short4v*)(&hA[r][c4]) = pa;
            *(short4v*)(&hB[r][c4]) = pb;
        }
    }
    __syncthreads();

    int budget = 1 << 22;

    for (int i = 0; i <= TSTEPS; ++i) {
        // ---- Phase 1: gate GEMMs (waves 0-2; 4 independent MFMA chains) ----
        if (wid < 3) {
            floatx4 a0a = {0,0,0,0}, a0b = {0,0,0,0}, a1a = {0,0,0,0}, a1b = {0,0,0,0};
            const int xp = i & 1;
#pragma unroll
            for (int kc = 0; kc < 16; ++kc) {
                short8 afh = *(const short8*)(&hA[lrow][kc*32 + lk]);
                if (i < TSTEPS) {
                    short8 afx = *(const short8*)(&x_tile[xp][lrow][kc*32 + lk]);
                    a0a = __builtin_amdgcn_mfma_f32_16x16x32_bf16(afx, wf0[kc], a0a, 0, 0, 0);
                    a0b = __builtin_amdgcn_mfma_f32_16x16x32_bf16(afh, rf0[kc], a0b, 0, 0, 0);
                }
                if (i >= 1) {
                    short8 afb = *(const short8*)(&hB[lrow][kc*32 + lk]);
                    a1a = __builtin_amdgcn_mfma_f32_16x16x32_bf16(afh, wf1[kc], a1a, 0, 0, 0);
                    a1b = __builtin_amdgcn_mfma_f32_16x16x32_bf16(afb, rf1[kc], a1b, 0, 0, 0);
                }
            }
            const int erow0 = (lane >> 4) << 2, ecol = lrow;
#pragma unroll
            for (int q = 0; q < 4; ++q) {
                proj[0][wid][erow0 + q][ecol] = sigmoidf_(a0a[q] + a0b[q] + bias0);
                proj[1][wid][erow0 + q][ecol] = sigmoidf_(a1a[q] + a1b[q] + bias1);
            }
        }
        __syncthreads();   // B1

        // ---- Phase 2: state update (1 cell/thread) + in-band u64 publish ----
        const int t = i - lyr;
        const bool act = lyr ? (i >= 1) : (i < TSTEPS);
        float h_ = 0.f, c_ = 0.f;
        if (act) {
            const float ig = proj[lyr][0][srow][scol];
            const float og = proj[lyr][1][srow][scol];
            const float zz = proj[lyr][2][srow][scol];
            c_ = creg*fgv + zz - ig;
            creg = c_;
            h_ = sigmoidf_(c_) - og;
            if (i < TSTEPS) {
                const unsigned hu = __float_as_uint(h_);
                const unsigned pu = (unsigned)__builtin_amdgcn_ds_swizzle((int)hu, 0x041F);
                unsigned pay;
                asm volatile("v_cvt_pk_bf16_f32 %0, %1, %2"
                             : "=v"(pay) : "v"(h_), "v"(__uint_as_float(pu)));
                if (!(scol & 1)) {
                    const size_t off = ((((size_t)lyr*4 + (t & 3))*8 + g)*32 + bidx)*64
                                     + srow*8 + (scol >> 1);
                    ring_st(ring + off, (u64)pay | ((u64)(unsigned)(t + 1) << 32));
                }
            }
        }

        // ---- Phase 3: one-trip sweep (detect == fetch) + x prefetch ----
        if (i < TSTEPS) {
            const u64* rb0 = ring + ((size_t)(i & 3)*8 + g)*2048;              // L0
            const u64* rb1 = ring + ((size_t)(4 + ((i - 1) & 3))*8 + g)*2048;  // L1
            const unsigned wantA = (unsigned)(i + 1);
            const unsigned wantB = (unsigned)i;
            const int kmax = (i >= 1) ? 16 : 8;
            u64 va[16];
#pragma unroll
            for (int k = 0; k < 16; ++k)
                if (k < kmax)
                    va[k] = ring_ld((k < 8) ? (rb0 + tid + (k << 8))
                                            : (rb1 + tid + ((k - 8) << 8)));
            floatx4 xr[4];
            const bool havex = (i + 1 < TSTEPS);
            if (havex) {
                const float* xp = x + ((size_t)(i + 1)*BATCH + g*GROWS)*HID;
#pragma unroll
                for (int k = 0; k < 4; ++k) {
                    const int idx = tid + (k << 8);
                    xr[k] = *(const floatx4*)(xp + (size_t)(idx >> 7)*HID + ((idx & 127) << 2));
                }
            }
            // tag check + batched conditional retries (no sleep, no drain)
            unsigned stale = 0;
#pragma unroll
            for (int k = 0; k < 16; ++k)
                if (k < kmax)
                    if ((unsigned)(va[k] >> 32) != ((k < 8) ? wantA : wantB))
                        stale |= (1u << k);
            while (__any((int)(stale != 0)) && budget > 0) {
#pragma unroll
                for (int k = 0; k < 16; ++k)
                    if (k < kmax && (stale & (1u << k)))
                        va[k] = ring_ld((k < 8) ? (rb0 + tid + (k << 8))
                                                : (rb1 + tid + ((k - 8) << 8)));
#pragma unroll
                for (int k = 0; k < 16; ++k)
                    if (k < kmax && (stale & (1u << k)))
                        if ((unsigned)(va[k] >> 32) == ((k < 8) ? wantA : wantB))
                            stale &= ~(1u << k);
                --budget;
            }
            // stash payloads into LDS tiles
#pragma unroll
            for (int k = 0; k < 16; ++k) {
                if (k < kmax) {
                    const int w = tid + ((k & 7) << 8);       // 0..2047 within layer
                    const int b = w >> 6, r = (w >> 3) & 7, u = w & 7;
                    unsigned* dst = (k < 8)
                        ? (unsigned*)(&hA[r][b*16 + u*2])
                        : (unsigned*)(&hB[r][b*16 + u*2]);
                    *dst = (unsigned)va[k];
                }
            }
            if (havex) {
                const int xq = (i + 1) & 1;
#pragma unroll
                for (int k = 0; k < 4; ++k) {
                    const int idx = tid + (k << 8);
                    short4v p4;
#pragma unroll
                    for (int j = 0; j < 4; ++j) p4[j] = (short)f2bf(xr[k][j]);
                    *(short4v*)(&x_tile[xq][idx >> 7][(idx & 127) << 2]) = p4;
                }
            }
        }

        // ---- Phase 4: out stores (off the critical wait; acks drain later) ----
        if (act && lyr == 1)
            out[((size_t)t*BATCH + g*GROWS + srow)*HID + col0 + scol] = h_;
        if (act && t == TSTEPS - 1) {
            const size_t fo = (size_t)TSTEPS*BATCH*HID
                            + ((size_t)lyr*BATCH + g*GROWS + srow)*HID + col0 + scol;
            out[fo] = h_;                               // h_f
            out[fo + (size_t)2*BATCH*HID] = c_;         // c_f
        }
        __syncthreads();   // B4
    }
}

extern "C" void kernel_launch(void* const* d_in, const int* in_sizes, int n_in,
                              void* d_out, int out_size, void* d_ws, size_t ws_size,
                              hipStream_t stream)
{
    (void)in_sizes; (void)n_in; (void)out_size; (void)ws_size;
    const float* x  = (const float*)d_in[0];
    const float* h0 = (const float*)d_in[1];
    const float* c0 = (const float*)d_in[2];
    const float* W  = (const float*)d_in[3];
    const float* R  = (const float*)d_in[4];
    const float* bi = (const float*)d_in[5];
    const float* bh = (const float*)d_in[6];
    const float* fw = (const float*)d_in[7];
    float* out = (float*)d_out;

    u64* ring = (u64*)d_ws;   // 2*4*8*2048*8B = 1 MB

    hipMemsetAsync(d_ws, 0, (size_t)2*4*8*2048*8, stream);  // hygiene (not required)

    sublstm_fused<<<dim3(NBLOCKS), dim3(NT), 0, stream>>>(
        x, W, R, bi, bh, fw, h0, c0, ring, out);
}

// Round 9
// 5100.958 us; speedup vs baseline: 2.3679x; 1.0139x over previous
//
#include <hip/hip_runtime.h>
#include <hip/hip_bf16.h>
#include <stdint.h>

// SubLSTM T=1024, B=64, H=512, GATE=3H, L=2 — fused 2-layer pipelined,
// round 9: sweep-first rounds; store-flight hidden under the x@W0 MFMA chain.
//
// 8 groups x 8 batch rows; 32 blocks/group (16 h-cols, both layers).
// Round i: L0 computes t=i, L1 computes t=i-1 (lag-1 layer pipeline).
// Exchange unit: u64 = (tag32<<32)|(2xbf16), relaxed agent-scope atomics
// (single-copy atomic, data IS the flag; no drains/sentinels/fences).
// Round structure (the change vs r8): the sweep for h0_{i-1}/h1_{i-2} —
// published by peers late in round i-1 — is ISSUED at the top of round i,
// then the exchange-independent chain a0a = x_i@W0 runs, THEN tags are
// checked: producer store flight propagates under the MFMAs, so retries are
// rare and cheap. Deferred out-stores (prev round's h) are issued with the
// sweep so their acks drain inside the same covered window.
// Barriers: B_mid (stash -> h-MFMAs), B_proj (proj -> state). All cross-round
// LDS hazards are separated by these two (audited; x_tile double-buffered).
// Ring depth 4, skew <= 1 round by sweep-all coupling => no tag alias;
// 32-bit tags; cross-replay stale accepts are bit-identical (deterministic);
// 0xAA poison never matches a wanted tag. Ring memset each call = hygiene.

#define TSTEPS 1024
#define BATCH  64
#define HID    512
#define GATE   1536
#define GROWS  8
#define NT     256
#define NBLOCKS 256

typedef unsigned long long u64;
typedef __attribute__((ext_vector_type(8))) short short8;
typedef __attribute__((ext_vector_type(4))) short short4v;
typedef __attribute__((ext_vector_type(4))) float floatx4;

__device__ __forceinline__ float sigmoidf_(float x) { return 1.0f / (1.0f + __expf(-x)); }

__device__ __forceinline__ unsigned short f2bf(float x) {
    union { float f; unsigned u; } v; v.f = x;
    unsigned r = v.u + 0x7FFFu + ((v.u >> 16) & 1u);   // RNE
    return (unsigned short)(r >> 16);
}

__device__ __forceinline__ short8 load_frag(const float* p) {
    floatx4 a = *(const floatx4*)p;
    floatx4 b = *(const floatx4*)(p + 4);
    short8 r;
#pragma unroll
    for (int j = 0; j < 4; ++j) { r[j] = (short)f2bf(a[j]); r[j+4] = (short)f2bf(b[j]); }
    return r;
}

__device__ __forceinline__ u64 ring_ld(const u64* p) {
    return __hip_atomic_load(p, __ATOMIC_RELAXED, __HIP_MEMORY_SCOPE_AGENT);
}
__device__ __forceinline__ void ring_st(u64* p, u64 v) {
    __hip_atomic_store(p, v, __ATOMIC_RELAXED, __HIP_MEMORY_SCOPE_AGENT);
}

// ---- preamble: x f32 -> bf16 (memory-bound; halves x fetch, removes f2bf
//      from the recurrent critical path) ----
__global__ __launch_bounds__(256) void xconvert(const float* __restrict__ x,
                                                unsigned short* __restrict__ xb) {
    const size_t i = ((size_t)blockIdx.x*256 + threadIdx.x) * 8;
    floatx4 a = *(const floatx4*)(x + i);
    floatx4 b = *(const floatx4*)(x + i + 4);
    short8 p;
#pragma unroll
    for (int j = 0; j < 4; ++j) { p[j] = (short)f2bf(a[j]); p[j+4] = (short)f2bf(b[j]); }
    *(short8*)(xb + i) = p;
}

__global__ __launch_bounds__(NT, 1) void sublstm_fused(
    const unsigned short* __restrict__ xb,
    const float* __restrict__ W,
    const float* __restrict__ R,
    const float* __restrict__ bi,
    const float* __restrict__ bh,
    const float* __restrict__ fw,
    const float* __restrict__ h0,
    const float* __restrict__ c0,
    u64* __restrict__ ring,        // [lyr 2][slot 4][grp 8][blk 32][row 8][unit 8]
    float* __restrict__ out)
{
    const int tid  = threadIdx.x;
    const int lane = tid & 63;
    const int wid  = tid >> 6;            // 0,1,2 = i/o/z gate waves; 3 = helper
    const int bid  = blockIdx.x;
    const int g    = bid & 7;             // batch group
    const int bidx = bid >> 3;            // 0..31: 16-col slice
    const int col0 = bidx << 4;

    __shared__ __align__(16) unsigned short x_tile[2][16][520];
    __shared__ __align__(16) unsigned short hA[16][520];    // h0_{i-1}
    __shared__ __align__(16) unsigned short hB[16][520];    // h1_{i-2}
    __shared__ float proj[2][3][16][17];

    for (int i = tid; i < 2*16*520; i += NT) ((unsigned short*)x_tile)[i] = 0;
    for (int i = tid; i < 16*520; i += NT) {
        ((unsigned short*)hA)[i] = 0;
        ((unsigned short*)hB)[i] = 0;
    }
    __syncthreads();   // zero-init fully visible before staging (r8 latent race)

    const int lrow = lane & 15;
    const int lk   = (lane >> 4) << 3;

    // ---- weights for both layers in regs (gate waves only) ----
    short8 wf0[16], rf0[16], wf1[16], rf1[16];
    float bias0 = 0.f, bias1 = 0.f;
    if (wid < 3) {
        const int wrow = wid*HID + col0 + lrow;
#pragma unroll
        for (int kc = 0; kc < 16; ++kc) {
            wf0[kc] = load_frag(W + (size_t)wrow*HID + kc*32 + lk);
            rf0[kc] = load_frag(R + (size_t)wrow*HID + kc*32 + lk);
            wf1[kc] = load_frag(W + ((size_t)GATE + wrow)*HID + kc*32 + lk);
            rf1[kc] = load_frag(R + ((size_t)GATE + wrow)*HID + kc*32 + lk);
        }
        bias0 = bi[wrow] + bh[wrow];
        bias1 = bi[GATE + wrow] + bh[GATE + wrow];
    }

    // ---- state: 1 cell per thread ----
    const int lyr  = tid >> 7;            // waves 0,1 -> L0; waves 2,3 -> L1
    const int srow = (tid >> 4) & 7;
    const int scol = tid & 15;
    const float fgv = sigmoidf_(fw[(size_t)lyr*HID + col0 + scol]);
    float creg = c0[((size_t)lyr*BATCH + g*GROWS + srow)*HID + col0 + scol];

    // ---- prologue: stage x_0 (bf16 copy) and h0 tiles (f32 -> bf16) ----
    {
        const unsigned short* xp = xb + (size_t)g*GROWS*HID;
        for (int w = tid; w < GROWS*HID/8; w += NT) {
            const int r = w >> 6, c8 = (w & 63) << 3;
            *(short8*)(&x_tile[0][r][c8]) = *(const short8*)(xp + (size_t)r*HID + c8);
        }
        const float* hp0 = h0 + (size_t)g*GROWS*HID;
        const float* hp1 = h0 + ((size_t)BATCH + g*GROWS)*HID;
        for (int w = tid; w < GROWS*HID/4; w += NT) {
            const int r = w >> 7, c4 = (w & 127) << 2;
            floatx4 va_ = *(const floatx4*)(hp0 + (size_t)r*HID + c4);
            floatx4 vb_ = *(const floatx4*)(hp1 + (size_t)r*HID + c4);
            short4v pa, pb;
#pragma unroll
            for (int j = 0; j < 4; ++j) { pa[j] = (short)f2bf(va_[j]); pb[j] = (short)f2bf(vb_[j]); }
            *(short4v*)(&hA[r][c4]) = pa;
            *(short4v*)(&hB[r][c4]) = pb;
        }
    }
    __syncthreads();

    int budget = 1 << 22;
    int pend_t = -1;                // deferred out-store (prev round's h,c)
    float pend_h = 0.f, pend_c = 0.f;

    for (int i = 0; i <= TSTEPS; ++i) {
        // ---- A: issue sweep + x prefetch + flush deferred out stores ----
        const int kmax = (i >= 2) ? 16 : ((i >= 1) ? 8 : 0);
        const u64* rb0 = ring + ((size_t)((i - 1) & 3)*8 + g)*2048;        // h0_{i-1}
        const u64* rb1 = ring + ((size_t)(4 + ((i - 2) & 3))*8 + g)*2048;  // h1_{i-2}
        u64 va[16];
#pragma unroll
        for (int k = 0; k < 16; ++k)
            if (k < kmax)
                va[k] = ring_ld((k < 8) ? (rb0 + tid + (k << 8))
                                        : (rb1 + tid + ((k - 8) << 8)));
        short8 xr0, xr1;
        const bool havex = (i + 1 < TSTEPS);
        if (havex) {
            const unsigned short* xp = xb + ((size_t)(i + 1)*BATCH + g*GROWS)*HID;
            xr0 = *(const short8*)(xp + (size_t)(tid >> 6)*HID + ((tid & 63) << 3));
            const int w1 = tid + 256;
            xr1 = *(const short8*)(xp + (size_t)(w1 >> 6)*HID + ((w1 & 63) << 3));
        }
        if (pend_t >= 0) {
            if (lyr == 1)
                out[((size_t)pend_t*BATCH + g*GROWS + srow)*HID + col0 + scol] = pend_h;
            if (pend_t == TSTEPS - 1) {
                const size_t fo = (size_t)TSTEPS*BATCH*HID
                                + ((size_t)lyr*BATCH + g*GROWS + srow)*HID + col0 + scol;
                out[fo] = pend_h;                          // h_f
                out[fo + (size_t)2*BATCH*HID] = pend_c;    // c_f
            }
            pend_t = -1;
        }
        __builtin_amdgcn_sched_barrier(0);   // pin issue order: loads/stores above

        // ---- B: exchange-independent chain a0a = x_i @ W0 (covers flight) ----
        floatx4 a0a = {0,0,0,0};
        if (wid < 3 && i < TSTEPS) {
            const int xq = i & 1;
#pragma unroll
            for (int kc = 0; kc < 16; ++kc) {
                short8 afx = *(const short8*)(&x_tile[xq][lrow][kc*32 + lk]);
                a0a = __builtin_amdgcn_mfma_f32_16x16x32_bf16(afx, wf0[kc], a0a, 0, 0, 0);
            }
        }
        __builtin_amdgcn_sched_barrier(0);   // keep check after the MFMA chain

        // ---- C: tag check + batched conditional retries + stash ----
        if (kmax) {
            const unsigned wantA = (unsigned)i;         // h0_{i-1} published tag i
            const unsigned wantB = (unsigned)(i - 1);   // h1_{i-2} published tag i-1
            unsigned stale = 0;
#pragma unroll
            for (int k = 0; k < 16; ++k)
                if (k < kmax)
                    if ((unsigned)(va[k] >> 32) != ((k < 8) ? wantA : wantB))
                        stale |= (1u << k);
            while (__any((int)(stale != 0)) && budget > 0) {
#pragma unroll
                for (int k = 0; k < 16; ++k)
                    if (k < kmax && (stale & (1u << k)))
                        va[k] = ring_ld((k < 8) ? (rb0 + tid + (k << 8))
                                                : (rb1 + tid + ((k - 8) << 8)));
#pragma unroll
                for (int k = 0; k < 16; ++k)
                    if (k < kmax && (stale & (1u << k)))
                        if ((unsigned)(va[k] >> 32) == ((k < 8) ? wantA : wantB))
                            stale &= ~(1u << k);
                --budget;
            }
#pragma unroll
            for (int k = 0; k < 16; ++k) {
                if (k < kmax) {
                    const int w = tid + ((k & 7) << 8);    // 0..2047 within layer
                    const int b = w >> 6, r = (w >> 3) & 7, u = w & 7;
                    unsigned* dst = (k < 8)
                        ? (unsigned*)(&hA[r][b*16 + u*2])
                        : (unsigned*)(&hB[r][b*16 + u*2]);
                    *dst = (unsigned)va[k];
                }
            }
        }
        if (havex) {
            const int xq = (i + 1) & 1;
            *(short8*)(&x_tile[xq][tid >> 6][(tid & 63) << 3]) = xr0;
            const int w1 = tid + 256;
            *(short8*)(&x_tile[xq][w1 >> 6][(w1 & 63) << 3]) = xr1;
        }
        __syncthreads();   // B_mid: stash visible before h-dependent MFMAs

        // ---- D: h-dependent chains (3 independent) + sigmoid -> proj ----
        if (wid < 3) {
            floatx4 a0b = {0,0,0,0}, a1a = {0,0,0,0}, a1b = {0,0,0,0};
#pragma unroll
            for (int kc = 0; kc < 16; ++kc) {
                short8 afh = *(const short8*)(&hA[lrow][kc*32 + lk]);
                if (i < TSTEPS)
                    a0b = __builtin_amdgcn_mfma_f32_16x16x32_bf16(afh, rf0[kc], a0b, 0, 0, 0);
                if (i >= 1) {
                    short8 afb = *(const short8*)(&hB[lrow][kc*32 + lk]);
                    a1a = __builtin_amdgcn_mfma_f32_16x16x32_bf16(afh, wf1[kc], a1a, 0, 0, 0);
                    a1b = __builtin_amdgcn_mfma_f32_16x16x32_bf16(afb, rf1[kc], a1b, 0, 0, 0);
                }
            }
            const int erow0 = (lane >> 4) << 2, ecol = lrow;
#pragma unroll
            for (int q = 0; q < 4; ++q) {
                proj[0][wid][erow0 + q][ecol] = sigmoidf_(a0a[q] + a0b[q] + bias0);
                proj[1][wid][erow0 + q][ecol] = sigmoidf_(a1a[q] + a1b[q] + bias1);
            }
        }
        __syncthreads();   // B_proj

        // ---- E: state update + in-band publish; out stores deferred ----
        const int t = i - lyr;
        const bool act = lyr ? (i >= 1) : (i < TSTEPS);
        if (act) {
            const float ig = proj[lyr][0][srow][scol];
            const float og = proj[lyr][1][srow][scol];
            const float zz = proj[lyr][2][srow][scol];
            const float c_ = creg*fgv + zz - ig;
            creg = c_;
            const float h_ = sigmoidf_(c_) - og;
            if (i < TSTEPS) {
                const unsigned hu = __float_as_uint(h_);
                const unsigned pu = (unsigned)__builtin_amdgcn_ds_swizzle((int)hu, 0x041F);
                unsigned pay;
                asm volatile("v_cvt_pk_bf16_f32 %0, %1, %2"
                             : "=v"(pay) : "v"(h_), "v"(__uint_as_float(pu)));
                if (!(scol & 1)) {
                    const size_t off = ((((size_t)lyr*4 + (t & 3))*8 + g)*32 + bidx)*64
                                     + srow*8 + (scol >> 1);
                    ring_st(ring + off, (u64)pay | ((u64)(unsigned)(t + 1) << 32));
                }
            }
            pend_t = t; pend_h = h_; pend_c = c_;
        }
    }

    // ---- post-loop: flush the last deferred stores (round TSTEPS, lyr1) ----
    if (pend_t >= 0) {
        if (lyr == 1)
            out[((size_t)pend_t*BATCH + g*GROWS + srow)*HID + col0 + scol] = pend_h;
        if (pend_t == TSTEPS - 1) {
            const size_t fo = (size_t)TSTEPS*BATCH*HID
                            + ((size_t)lyr*BATCH + g*GROWS + srow)*HID + col0 + scol;
            out[fo] = pend_h;
            out[fo + (size_t)2*BATCH*HID] = pend_c;
        }
    }
}

extern "C" void kernel_launch(void* const* d_in, const int* in_sizes, int n_in,
                              void* d_out, int out_size, void* d_ws, size_t ws_size,
                              hipStream_t stream)
{
    (void)in_sizes; (void)n_in; (void)out_size; (void)ws_size;
    const float* x  = (const float*)d_in[0];
    const float* h0 = (const float*)d_in[1];
    const float* c0 = (const float*)d_in[2];
    const float* W  = (const float*)d_in[3];
    const float* R  = (const float*)d_in[4];
    const float* bi = (const float*)d_in[5];
    const float* bh = (const float*)d_in[6];
    const float* fw = (const float*)d_in[7];
    float* out = (float*)d_out;

    u64* ring = (u64*)d_ws;                                             // 1 MB
    unsigned short* xbuf = (unsigned short*)((char*)d_ws + (2u << 20)); // 64 MB

    hipMemsetAsync(d_ws, 0, (size_t)2*4*8*2048*8, stream);  // hygiene

    xconvert<<<dim3(TSTEPS*BATCH*HID/(256*8)), dim3(256), 0, stream>>>(x, xbuf);

    sublstm_fused<<<dim3(NBLOCKS), dim3(NT), 0, stream>>>(
        xbuf, W, R, bi, bh, fw, h0, c0, ring, out);
}